// Round 10
// baseline (341.506 us; speedup 1.0000x reference)
//
#include <hip/hip_runtime.h>
#include <math.h>

#define NBF 4104             // B*F = 8*513
#define XT_FLOATS 16809984   // 8*513*8*512

// Static device scratch; fully overwritten before read each call -> deterministic.
__device__ float d_partials[NBF];
__device__ float d_scales[8];

// Phase-A macros. All accumulators are PLAIN LOCALS with compile-time indices.
#define DIAG(Q,M)    yr = rw*xv[M].x; yi = rw*xv[M].y; \
                     accd[Q] += yr*xv[M].x + yi*xv[M].y;
#define CROSS(P,M,N) accr[P] += yr*xv[N].x + yi*xv[N].y; \
                     acci[P] += yi*xv[N].x - yr*xv[N].y;
#define VSTD(Q,M)    s_V[k][M][M] = make_float2(accd[Q]*invT, 0.f);
#define VSTO(P,M,N)  { const float vr=accr[P]*invT, vi=acci[P]*invT; \
                       s_V[k][M][N] = make_float2(vr,  vi);          \
                       s_V[k][N][M] = make_float2(vr, -vi); }

// launch_bounds law (empirical): VGPR cap = 256/arg2. arg2=2 -> 128.
// r9: chunked r-prefetch keeps live set under 128 -> zero spill, FETCH ~= inputs.
__global__ __launch_bounds__(256, 2) void iss_main(
    const float* __restrict__ g_r,
    const float* __restrict__ g_xre,
    const float* __restrict__ g_xim,
    const float* __restrict__ g_Qre,
    const float* __restrict__ g_Qim,
    float* __restrict__ g_out,
    const int qmode,        // 2 = interleaved re,im pairs; 1 = real part only
    const int xt_off)       // float offset where the xt region begins
{
    __shared__ float2 s_x[8][512];     // packed (re,im), 32 KB
    __shared__ float2 s_V[8][8][9];    // padded row stride
    __shared__ float2 s_Q[8][8];
    __shared__ float  s_part[4];

    const int tid = threadIdx.x;
    const int bf  = blockIdx.x;
    const size_t base = (size_t)bf * 4096;

    // ---- stage x into packed LDS (float4 global loads, coalesced); Q into s_Q ----
    {
        const float4* xr4 = (const float4*)(g_xre + base);
        const float4* xi4 = (const float4*)(g_xim + base);
        float4* sx4 = (float4*)&s_x[0][0];
        #pragma unroll
        for (int i = 0; i < 4; ++i) {
            const int idx = tid + (i << 8);
            const float4 xr = xr4[idx], xi = xi4[idx];
            sx4[2*idx]   = make_float4(xr.x, xi.x, xr.y, xi.y);
            sx4[2*idx+1] = make_float4(xr.z, xi.z, xr.w, xi.w);
        }
        if (tid < 64)
            s_Q[tid>>3][tid&7] = make_float2(g_Qre[(size_t)bf*64 + tid],
                                             g_Qim[(size_t)bf*64 + tid]);
    }
    __syncthreads();

    // ---- phase A: V[k] = (1/T) sum_t max(r,1e-3) x x^H, row-group split ----
    // 16 lanes per (g,k) group; g0 owns rows {0,3,5,6}, g1 rows {1,2,4,7}.
    const int ts = tid & 15;
    const int k  = (tid >> 4) & 7;
    const int g  = tid >> 7;          // wave-uniform

    float accd[4] = {0,0,0,0};
    float accr[14], acci[14];
    #pragma unroll
    for (int p = 0; p < 14; ++p) { accr[p] = 0.f; acci[p] = 0.f; }

    {
        const float* rrow = g_r + base + (k << 9) + ts;
        #pragma unroll
        for (int c = 0; c < 4; ++c) {
            // 8 r-loads per chunk, consumed immediately (keeps live set < 128 cap)
            float rb[8];
            #pragma unroll
            for (int i = 0; i < 8; ++i) rb[i] = rrow[((c << 3) + i) << 4];

            if (g == 0) {
                #pragma unroll
                for (int i = 0; i < 8; ++i) {
                    const int t = ts + (((c << 3) + i) << 4);
                    const float rw = fmaxf(rb[i], 1e-3f);
                    float2 xv[8];
                    #pragma unroll
                    for (int n = 0; n < 8; ++n) xv[n] = s_x[n][t];
                    float yr, yi;
                    DIAG(0,0) CROSS(0,0,1) CROSS(1,0,2) CROSS(2,0,3) CROSS(3,0,4)
                              CROSS(4,0,5) CROSS(5,0,6) CROSS(6,0,7)
                    DIAG(1,3) CROSS(7,3,4) CROSS(8,3,5) CROSS(9,3,6) CROSS(10,3,7)
                    DIAG(2,5) CROSS(11,5,6) CROSS(12,5,7)
                    DIAG(3,6) CROSS(13,6,7)
                }
            } else {
                #pragma unroll
                for (int i = 0; i < 8; ++i) {
                    const int t = ts + (((c << 3) + i) << 4);
                    const float rw = fmaxf(rb[i], 1e-3f);
                    float2 xv[8];
                    #pragma unroll
                    for (int n = 0; n < 8; ++n) xv[n] = s_x[n][t];
                    float yr, yi;
                    DIAG(0,1) CROSS(0,1,2) CROSS(1,1,3) CROSS(2,1,4) CROSS(3,1,5)
                              CROSS(4,1,6) CROSS(5,1,7)
                    DIAG(1,2) CROSS(6,2,3) CROSS(7,2,4) CROSS(8,2,5) CROSS(9,2,6)
                              CROSS(10,2,7)
                    DIAG(2,4) CROSS(11,4,5) CROSS(12,4,6) CROSS(13,4,7)
                    DIAG(3,7)
                }
            }
        }
    }

    // reduce across the 16 lanes sharing (g,k): xor offsets 1..8 stay in-group
    #pragma unroll
    for (int q = 0; q < 4; ++q) {
        #pragma unroll
        for (int off = 1; off < 16; off <<= 1) accd[q] += __shfl_xor(accd[q], off, 64);
    }
    #pragma unroll
    for (int p = 0; p < 14; ++p) {
        #pragma unroll
        for (int off = 1; off < 16; off <<= 1) accr[p] += __shfl_xor(accr[p], off, 64);
        #pragma unroll
        for (int off = 1; off < 16; off <<= 1) acci[p] += __shfl_xor(acci[p], off, 64);
    }

    if (ts == 0) {
        const float invT = 1.0f / 512.0f;
        if (g == 0) {
            VSTD(0,0) VSTO(0,0,1) VSTO(1,0,2) VSTO(2,0,3) VSTO(3,0,4)
                      VSTO(4,0,5) VSTO(5,0,6) VSTO(6,0,7)
            VSTD(1,3) VSTO(7,3,4) VSTO(8,3,5) VSTO(9,3,6) VSTO(10,3,7)
            VSTD(2,5) VSTO(11,5,6) VSTO(12,5,7)
            VSTD(3,6) VSTO(13,6,7)
        } else {
            VSTD(0,1) VSTO(0,1,2) VSTO(1,1,3) VSTO(2,1,4) VSTO(3,1,5)
                      VSTO(4,1,6) VSTO(5,1,7)
            VSTD(1,2) VSTO(6,2,3) VSTO(7,2,4) VSTO(8,2,5) VSTO(9,2,6)
                      VSTO(10,2,7)
            VSTD(2,4) VSTO(11,4,5) VSTO(12,4,6) VSTO(13,4,7)
            VSTD(3,7)
        }
    }
    __syncthreads();

    // ---- diag fix: add max(trace,1)*EPS (trace spans both row-groups) ----
    if (tid < 64) {
        const int kq = tid >> 3, mq = tid & 7;
        const float dv = s_V[kq][mq][mq].x;
        float tr = dv;
        #pragma unroll
        for (int off = 1; off < 8; off <<= 1) tr += __shfl_xor(tr, off, 64);
        s_V[kq][mq][mq].x = dv + fmaxf(tr, 1.0f) * 1e-6f;
    }
    __syncthreads();

    // ---- phase B: wave-synchronous, zero barriers, all waves redundant ----
    {
        const int lane = tid & 63;
        const int kp = lane >> 3, mm = lane & 7;
        float vRr[8], vRi[8];
        #pragma unroll
        for (int n = 0; n < 8; ++n) {
            const float2 V = s_V[kp][mm][n];
            vRr[n] = V.x; vRi[n] = V.y;
        }
        const float2 Q0 = s_Q[kp][mm];
        float qre = Q0.x, qim = Q0.y;

        #pragma unroll
        for (int step = 0; step < 16; ++step) {
            const int kk = step & 7;
            float qnr[8], qni[8];
            #pragma unroll
            for (int n = 0; n < 8; ++n) {
                qnr[n] = __shfl(qre, (kk<<3)+n, 64);
                qni[n] = __shfl(qim, (kk<<3)+n, 64);
            }
            const float qmr = __shfl(qre, (kk<<3)+mm, 64);
            const float qmi = __shfl(qim, (kk<<3)+mm, 64);

            float vqr = 0.f, vqi = 0.f;
            #pragma unroll
            for (int n = 0; n < 8; ++n) {
                vqr += vRr[n]*qnr[n] + vRi[n]*qni[n];   // V * conj(q)
                vqi += vRi[n]*qnr[n] - vRr[n]*qni[n];
            }
            float p   = qmr*vqr - qmi*vqi;              // Re(q_m * Vq_m)
            float tre = qre*vqr - qim*vqi;              // Q_own * Vq_own
            float tim = qre*vqi + qim*vqr;
            #pragma unroll
            for (int off = 1; off < 8; off <<= 1) {
                p   += __shfl_xor(p,   off, 64);
                tre += __shfl_xor(tre, off, 64);
                tim += __shfl_xor(tim, off, 64);
            }
            const float qvq = fmaxf(p, 1e-6f);
            float vr_, vi_;
            if (kp == kk) { vr_ = 1.0f - rsqrtf(qvq); vi_ = 0.f; }
            else { const float inv = 1.0f / qvq; vr_ = tre*inv; vi_ = tim*inv; }
            qre -= vr_*qmr - vi_*qmi;
            qim -= vr_*qmi + vi_*qmr;
        }

        if (tid < 64) {
            s_Q[kp][mm] = make_float2(qre, qim);
            if (qmode == 2) {
                g_out[(size_t)bf*128 + tid*2]     = qre;
                g_out[(size_t)bf*128 + tid*2 + 1] = qim;
            } else {
                g_out[(size_t)bf*64 + tid] = qre;
            }
        }
    }
    __syncthreads();

    // ---- phase C: xt = |Q x|^2, t-major. Thread owns t = {tid, tid+256};
    //      x loaded ONCE into regs (16 clean b64: consecutive-t = 2-way = free),
    //      Q via all-lane broadcast reads, stores coalesced per m-row.
    //      (r9's m-major version: 128 reads/thread at 4-way conflict = the 5.3M
    //       SQ_LDS_BANK_CONFLICT constant since r6.) ----
    float lsum = 0.f;
    float* out_xt = g_out + xt_off;
    {
        const int t0 = tid, t1 = tid + 256;
        float2 xva[8], xvb[8];
        #pragma unroll
        for (int n = 0; n < 8; ++n) { xva[n] = s_x[n][t0]; xvb[n] = s_x[n][t1]; }
        #pragma unroll
        for (int m = 0; m < 8; ++m) {
            float2 qv[8];
            #pragma unroll
            for (int n = 0; n < 8; ++n) qv[n] = s_Q[m][n];   // broadcast (free)
            float ar = 0.f, ai = 0.f, br = 0.f, bi = 0.f;
            #pragma unroll
            for (int n = 0; n < 8; ++n) {
                ar += qv[n].x*xva[n].x - qv[n].y*xva[n].y;
                ai += qv[n].x*xva[n].y + qv[n].y*xva[n].x;
                br += qv[n].x*xvb[n].x - qv[n].y*xvb[n].y;
                bi += qv[n].x*xvb[n].y + qv[n].y*xvb[n].x;
            }
            const float pa = ar*ar + ai*ai;
            const float pb = br*br + bi*bi;
            out_xt[base + (m << 9) + t0] = pa;
            out_xt[base + (m << 9) + t1] = pb;
            lsum += pa + pb;
        }
    }
    #pragma unroll
    for (int off = 32; off >= 1; off >>= 1) lsum += __shfl_xor(lsum, off, 64);
    if ((tid & 63) == 0) s_part[tid >> 6] = lsum;
    __syncthreads();
    if (tid == 0) d_partials[bf] = s_part[0] + s_part[1] + s_part[2] + s_part[3];
}

__global__ __launch_bounds__(256) void iss_scale()
{
    const int b = blockIdx.x, tid = threadIdx.x;
    __shared__ float sp[4];
    float s = 0.f;
    for (int i = tid; i < 513; i += 256) s += d_partials[b*513 + i];
    #pragma unroll
    for (int off = 32; off >= 1; off >>= 1) s += __shfl_xor(s, off, 64);
    if ((tid & 63) == 0) sp[tid >> 6] = s;
    __syncthreads();
    if (tid == 0) d_scales[b] = (sp[0]+sp[1]+sp[2]+sp[3]) / (513.0f * 8.0f * 512.0f);
}

__global__ __launch_bounds__(256) void iss_norm(
    float* __restrict__ g_out,
    const int nq4,     // Q region in float4s  (= xt_off/4)
    const int qb4,     // float4s per batch in Q region
    const int nt4)     // total float4s (= out_size/4)
{
    float4* o4 = (float4*)g_out;
    for (int i = blockIdx.x*256 + threadIdx.x; i < nt4; i += gridDim.x*256) {
        float s;
        if (i < nq4) {
            const int b = i / qb4;
            s = rsqrtf(fmaxf(d_scales[b], 1e-6f));
        } else {
            const int j = i - nq4;
            const int b = j / 525312;          // xt float4s per batch
            s = 1.0f / d_scales[b];
        }
        float4 v = o4[i];
        v.x *= s; v.y *= s; v.z *= s; v.w *= s;
        o4[i] = v;
    }
}

extern "C" void kernel_launch(void* const* d_in, const int* in_sizes, int n_in,
                              void* d_out, int out_size, void* d_ws, size_t ws_size,
                              hipStream_t stream) {
    const float* r   = (const float*)d_in[0];
    const float* xre = (const float*)d_in[1];
    const float* xim = (const float*)d_in[2];
    const float* Qre = (const float*)d_in[3];
    const float* Qim = (const float*)d_in[4];
    float* out = (float*)d_out;

    const int q_floats = out_size - XT_FLOATS;
    const int qmode  = (q_floats >= 525312) ? 2 : 1;
    const int xt_off = (qmode == 2) ? 525312 : 262656;
    const int nq4 = xt_off / 4;
    const int qb4 = xt_off / (4 * 8);
    const int nt4 = nq4 + XT_FLOATS / 4;

    iss_main <<<NBF, 256, 0, stream>>>(r, xre, xim, Qre, Qim, out, qmode, xt_off);
    iss_scale<<<8,   256, 0, stream>>>();
    iss_norm <<<4096,256, 0, stream>>>(out, nq4, qb4, nt4);
}

// Round 11
// 292.200 us; speedup vs baseline: 1.1687x; 1.1687x over previous
//
#include <hip/hip_runtime.h>
#include <math.h>

#define NBF 4104             // B*F = 8*513
#define XT_FLOATS 16809984   // 8*513*8*512

// Static device scratch; fully overwritten before read each call -> deterministic.
__device__ float d_partials[NBF];
__device__ float d_scales[8];

// Phase-A cross-term: entry (M,N) re += ar*xn_r + ai*xn_i ; im += ai*xn_r - ar*xn_i
// (ar,ai = w * x_m). All accumulators plain locals, compile-time indices.
#define PA_CROSS(P,N,C) cr[P] += ar*xr2[N].C + ai*xi2[N].C; \
                        ci[P] += ai*xr2[N].C - ar*xi2[N].C;

// wave g owns rows {g, 7-g}: 2 diag + 7 off-diag each (9+9+9+9 = 36 Hermitian entries)
#define PA_G0(C) { const float rw = fmaxf(rv.C, 1e-3f); float ar, ai;          \
    ar = rw*xr2[0].C; ai = rw*xi2[0].C;                                        \
    d0 += ar*xr2[0].C + ai*xi2[0].C;                                           \
    PA_CROSS(0,1,C) PA_CROSS(1,2,C) PA_CROSS(2,3,C) PA_CROSS(3,4,C)            \
    PA_CROSS(4,5,C) PA_CROSS(5,6,C) PA_CROSS(6,7,C)                            \
    ar = rw*xr2[7].C; ai = rw*xi2[7].C;                                        \
    d1 += ar*xr2[7].C + ai*xi2[7].C; }

#define PA_G1(C) { const float rw = fmaxf(rv.C, 1e-3f); float ar, ai;          \
    ar = rw*xr2[1].C; ai = rw*xi2[1].C;                                        \
    d0 += ar*xr2[1].C + ai*xi2[1].C;                                           \
    PA_CROSS(0,2,C) PA_CROSS(1,3,C) PA_CROSS(2,4,C) PA_CROSS(3,5,C)            \
    PA_CROSS(4,6,C) PA_CROSS(5,7,C)                                            \
    ar = rw*xr2[6].C; ai = rw*xi2[6].C;                                        \
    d1 += ar*xr2[6].C + ai*xi2[6].C;                                           \
    PA_CROSS(6,7,C) }

#define PA_G2(C) { const float rw = fmaxf(rv.C, 1e-3f); float ar, ai;          \
    ar = rw*xr2[2].C; ai = rw*xi2[2].C;                                        \
    d0 += ar*xr2[2].C + ai*xi2[2].C;                                           \
    PA_CROSS(0,3,C) PA_CROSS(1,4,C) PA_CROSS(2,5,C) PA_CROSS(3,6,C)            \
    PA_CROSS(4,7,C)                                                            \
    ar = rw*xr2[5].C; ai = rw*xi2[5].C;                                        \
    d1 += ar*xr2[5].C + ai*xi2[5].C;                                           \
    PA_CROSS(5,6,C) PA_CROSS(6,7,C) }

#define PA_G3(C) { const float rw = fmaxf(rv.C, 1e-3f); float ar, ai;          \
    ar = rw*xr2[3].C; ai = rw*xi2[3].C;                                        \
    d0 += ar*xr2[3].C + ai*xi2[3].C;                                           \
    PA_CROSS(0,4,C) PA_CROSS(1,5,C) PA_CROSS(2,6,C) PA_CROSS(3,7,C)            \
    ar = rw*xr2[4].C; ai = rw*xi2[4].C;                                        \
    d1 += ar*xr2[4].C + ai*xi2[4].C;                                           \
    PA_CROSS(4,5,C) PA_CROSS(5,6,C) PA_CROSS(6,7,C) }

#define VSTD2(D,M)  s_V[k][M][M] = make_float2((D)*invT, 0.f);
#define VSTO2(P,M,N){ const float vr=cr[P]*invT, vi=ci[P]*invT;  \
                      s_V[k][M][N] = make_float2(vr,  vi);       \
                      s_V[k][N][M] = make_float2(vr, -vi); }

// launch_bounds law (empirical): VGPR cap = 256/arg2. arg=3 -> 85.
// New live set ~65 (16 acc + 32 xv + addr) -> real margin under 85, no spill.
// No s_x in LDS (phase A/C read x from global, L1/L2-resident) -> LDS 5.1 KB,
// occupancy = VGPR-bound 6 waves/SIMD (24 waves/CU), 1.5x round 10.
__global__ __launch_bounds__(256, 3) void iss_main(
    const float* __restrict__ g_r,
    const float* __restrict__ g_xre,
    const float* __restrict__ g_xim,
    const float* __restrict__ g_Qre,
    const float* __restrict__ g_Qim,
    float* __restrict__ g_out,
    const int qmode,        // 2 = interleaved re,im pairs; 1 = real part only
    const int xt_off)       // float offset where the xt region begins
{
    __shared__ float2 s_V[8][8][9];    // padded row stride
    __shared__ float2 s_Q[8][8];
    __shared__ float  s_part[4];

    const int tid = threadIdx.x;
    const int bf  = blockIdx.x;
    const size_t base = (size_t)bf * 4096;

    const float* xre = g_xre + base;
    const float* xim = g_xim + base;

    if (tid < 64)
        s_Q[tid>>3][tid&7] = make_float2(g_Qre[(size_t)bf*64 + tid],
                                         g_Qim[(size_t)bf*64 + tid]);

    // ---- phase A: V[k] = (1/T) sum_t max(r,1e-3) x x^H -------------------
    // tid = (g<<6)|(k<<3)|tl : wave g owns row-pair {g,7-g}; 8 t-lanes per (g,k);
    // each lane handles t = {16i + 2tl, +1} for i=0..31 (float2 loads, coalesced,
    // broadcast across the 8 k-subgroups of the wave -> 1 line per load).
    const int tl = tid & 7;
    const int k  = (tid >> 3) & 7;
    const int g  = tid >> 6;          // wave index, uniform

    float d0 = 0.f, d1 = 0.f;
    float cr[7], ci[7];
    #pragma unroll
    for (int p = 0; p < 7; ++p) { cr[p] = 0.f; ci[p] = 0.f; }

    {
        const float* rrow = g_r + base + (k << 9);
        #pragma unroll 4
        for (int i = 0; i < 32; ++i) {
            const int t = (i << 4) + (tl << 1);
            const float2 rv = *(const float2*)&rrow[t];
            float2 xr2[8], xi2[8];
            #pragma unroll
            for (int n = 0; n < 8; ++n) {
                xr2[n] = *(const float2*)&xre[(n << 9) + t];
                xi2[n] = *(const float2*)&xim[(n << 9) + t];
            }
            if      (g == 0) { PA_G0(x) PA_G0(y) }
            else if (g == 1) { PA_G1(x) PA_G1(y) }
            else if (g == 2) { PA_G2(x) PA_G2(y) }
            else             { PA_G3(x) PA_G3(y) }
        }
    }

    // reduce across the 8 t-lanes of each (g,k): xor 1,2,4 stay in-group
    #pragma unroll
    for (int off = 1; off < 8; off <<= 1) {
        d0 += __shfl_xor(d0, off, 64);
        d1 += __shfl_xor(d1, off, 64);
        #pragma unroll
        for (int p = 0; p < 7; ++p) {
            cr[p] += __shfl_xor(cr[p], off, 64);
            ci[p] += __shfl_xor(ci[p], off, 64);
        }
    }

    if (tl == 0) {
        const float invT = 1.0f / 512.0f;
        if (g == 0) {
            VSTD2(d0,0) VSTO2(0,0,1) VSTO2(1,0,2) VSTO2(2,0,3) VSTO2(3,0,4)
                        VSTO2(4,0,5) VSTO2(5,0,6) VSTO2(6,0,7)
            VSTD2(d1,7)
        } else if (g == 1) {
            VSTD2(d0,1) VSTO2(0,1,2) VSTO2(1,1,3) VSTO2(2,1,4) VSTO2(3,1,5)
                        VSTO2(4,1,6) VSTO2(5,1,7)
            VSTD2(d1,6) VSTO2(6,6,7)
        } else if (g == 2) {
            VSTD2(d0,2) VSTO2(0,2,3) VSTO2(1,2,4) VSTO2(2,2,5) VSTO2(3,2,6)
                        VSTO2(4,2,7)
            VSTD2(d1,5) VSTO2(5,5,6) VSTO2(6,5,7)
        } else {
            VSTD2(d0,3) VSTO2(0,3,4) VSTO2(1,3,5) VSTO2(2,3,6) VSTO2(3,3,7)
            VSTD2(d1,4) VSTO2(4,4,5) VSTO2(5,4,6) VSTO2(6,4,7)
        }
    }
    __syncthreads();

    // ---- diag fix + phase B: SINGLE WAVE (waves 1-3 skip to the barrier;
    //      their pipes are filled by the 6 co-resident blocks) ----
    if (tid < 64) {
        // diag fix: add max(trace,1)*EPS
        {
            const int kq = tid >> 3, mq = tid & 7;
            const float dv = s_V[kq][mq][mq].x;
            float tr = dv;
            #pragma unroll
            for (int off = 1; off < 8; off <<= 1) tr += __shfl_xor(tr, off, 64);
            s_V[kq][mq][mq].x = dv + fmaxf(tr, 1.0f) * 1e-6f;
        }
        // phase B: lane (kp,mm) owns Q[kp][mm]; V row in regs; zero barriers
        const int kp = tid >> 3, mm = tid & 7;
        float vRr[8], vRi[8];
        #pragma unroll
        for (int n = 0; n < 8; ++n) {
            const float2 V = s_V[kp][mm][n];
            vRr[n] = V.x; vRi[n] = V.y;
        }
        const float2 Q0 = s_Q[kp][mm];
        float qre = Q0.x, qim = Q0.y;

        #pragma unroll
        for (int step = 0; step < 16; ++step) {
            const int kk = step & 7;
            float qnr[8], qni[8];
            #pragma unroll
            for (int n = 0; n < 8; ++n) {
                qnr[n] = __shfl(qre, (kk<<3)+n, 64);
                qni[n] = __shfl(qim, (kk<<3)+n, 64);
            }
            const float qmr = __shfl(qre, (kk<<3)+mm, 64);
            const float qmi = __shfl(qim, (kk<<3)+mm, 64);

            float vqr = 0.f, vqi = 0.f;
            #pragma unroll
            for (int n = 0; n < 8; ++n) {
                vqr += vRr[n]*qnr[n] + vRi[n]*qni[n];   // V * conj(q)
                vqi += vRi[n]*qnr[n] - vRr[n]*qni[n];
            }
            float p   = qmr*vqr - qmi*vqi;              // Re(q_m * Vq_m)
            float tre = qre*vqr - qim*vqi;              // Q_own * Vq_own
            float tim = qre*vqi + qim*vqr;
            #pragma unroll
            for (int off = 1; off < 8; off <<= 1) {
                p   += __shfl_xor(p,   off, 64);
                tre += __shfl_xor(tre, off, 64);
                tim += __shfl_xor(tim, off, 64);
            }
            const float qvq = fmaxf(p, 1e-6f);
            float vr_, vi_;
            if (kp == kk) { vr_ = 1.0f - rsqrtf(qvq); vi_ = 0.f; }
            else { const float inv = 1.0f / qvq; vr_ = tre*inv; vi_ = tim*inv; }
            qre -= vr_*qmr - vi_*qmi;
            qim -= vr_*qmi + vi_*qmr;
        }

        s_Q[kp][mm] = make_float2(qre, qim);
        if (qmode == 2) {
            g_out[(size_t)bf*128 + tid*2]     = qre;
            g_out[(size_t)bf*128 + tid*2 + 1] = qim;
        } else {
            g_out[(size_t)bf*64 + tid] = qre;
        }
    }
    __syncthreads();

    // ---- phase C: xt = |Q x|^2, t-major from GLOBAL (coalesced; L2-hit),
    //      Q via LDS broadcast, stores coalesced ----
    float lsum = 0.f;
    float* out_xt = g_out + xt_off;
    {
        const int t0 = tid, t1 = tid + 256;
        float xra[8], xia[8], xrb[8], xib[8];
        #pragma unroll
        for (int n = 0; n < 8; ++n) {
            xra[n] = xre[(n << 9) + t0];  xia[n] = xim[(n << 9) + t0];
            xrb[n] = xre[(n << 9) + t1];  xib[n] = xim[(n << 9) + t1];
        }
        #pragma unroll
        for (int m = 0; m < 8; ++m) {
            float2 qv[8];
            #pragma unroll
            for (int n = 0; n < 8; ++n) qv[n] = s_Q[m][n];   // broadcast (free)
            float ar = 0.f, ai = 0.f, br = 0.f, bi = 0.f;
            #pragma unroll
            for (int n = 0; n < 8; ++n) {
                ar += qv[n].x*xra[n] - qv[n].y*xia[n];
                ai += qv[n].x*xia[n] + qv[n].y*xra[n];
                br += qv[n].x*xrb[n] - qv[n].y*xib[n];
                bi += qv[n].x*xib[n] + qv[n].y*xrb[n];
            }
            const float pa = ar*ar + ai*ai;
            const float pb = br*br + bi*bi;
            out_xt[base + (m << 9) + t0] = pa;
            out_xt[base + (m << 9) + t1] = pb;
            lsum += pa + pb;
        }
    }
    #pragma unroll
    for (int off = 32; off >= 1; off >>= 1) lsum += __shfl_xor(lsum, off, 64);
    if ((tid & 63) == 0) s_part[tid >> 6] = lsum;
    __syncthreads();
    if (tid == 0) d_partials[bf] = s_part[0] + s_part[1] + s_part[2] + s_part[3];
}

__global__ __launch_bounds__(256) void iss_scale()
{
    const int b = blockIdx.x, tid = threadIdx.x;
    __shared__ float sp[4];
    float s = 0.f;
    for (int i = tid; i < 513; i += 256) s += d_partials[b*513 + i];
    #pragma unroll
    for (int off = 32; off >= 1; off >>= 1) s += __shfl_xor(s, off, 64);
    if ((tid & 63) == 0) sp[tid >> 6] = s;
    __syncthreads();
    if (tid == 0) d_scales[b] = (sp[0]+sp[1]+sp[2]+sp[3]) / (513.0f * 8.0f * 512.0f);
}

__global__ __launch_bounds__(256) void iss_norm(
    float* __restrict__ g_out,
    const int nq4,     // Q region in float4s  (= xt_off/4)
    const int qb4,     // float4s per batch in Q region
    const int nt4)     // total float4s (= out_size/4)
{
    float4* o4 = (float4*)g_out;
    for (int i = blockIdx.x*256 + threadIdx.x; i < nt4; i += gridDim.x*256) {
        float s;
        if (i < nq4) {
            const int b = i / qb4;
            s = rsqrtf(fmaxf(d_scales[b], 1e-6f));
        } else {
            const int j = i - nq4;
            const int b = j / 525312;          // xt float4s per batch
            s = 1.0f / d_scales[b];
        }
        float4 v = o4[i];
        v.x *= s; v.y *= s; v.z *= s; v.w *= s;
        o4[i] = v;
    }
}

extern "C" void kernel_launch(void* const* d_in, const int* in_sizes, int n_in,
                              void* d_out, int out_size, void* d_ws, size_t ws_size,
                              hipStream_t stream) {
    const float* r   = (const float*)d_in[0];
    const float* xre = (const float*)d_in[1];
    const float* xim = (const float*)d_in[2];
    const float* Qre = (const float*)d_in[3];
    const float* Qim = (const float*)d_in[4];
    float* out = (float*)d_out;

    const int q_floats = out_size - XT_FLOATS;
    const int qmode  = (q_floats >= 525312) ? 2 : 1;
    const int xt_off = (qmode == 2) ? 525312 : 262656;
    const int nq4 = xt_off / 4;
    const int qb4 = xt_off / (4 * 8);
    const int nt4 = nq4 + XT_FLOATS / 4;

    iss_main <<<NBF, 256, 0, stream>>>(r, xre, xim, Qre, Qim, out, qmode, xt_off);
    iss_scale<<<8,   256, 0, stream>>>();
    iss_norm <<<4096,256, 0, stream>>>(out, nq4, qb4, nt4);
}